// Round 7
// baseline (286.195 us; speedup 1.0000x reference)
//
#include <hip/hip_runtime.h>
#include <cstdint>

constexpr int N_FEAT  = 8;
constexpr int E_FEAT  = 4;
constexpr int NUM_IN  = 2 * (N_FEAT + 2) + E_FEAT + 1;  // 25
constexpr int NUM_OUT = 2 * N_FEAT + E_FEAT;            // 20
constexpr int M       = 4;    // edges per thread: 4 FMA chains per weight fetch
constexpr int BLK     = 256;

// M=4 raises FMA-work per fetched weight dword from 2 cycles (rounds 4-6:
// VALUBusy ~40%, scalar-pipe starvation) to 8 cycles. waves_per_eu(2,2)
// grants the 256-VGPR budget for x[4][25]+h[4][25] resident.
__global__ __launch_bounds__(BLK)
__attribute__((amdgpu_waves_per_eu(2, 2)))
void edge_mlp(
    const float* __restrict__ r,
    const float* __restrict__ a_data,
    const float* __restrict__ a_mat,
    const float* __restrict__ a_inf,
    const float* __restrict__ b_data,
    const float* __restrict__ b_mat,
    const float* __restrict__ b_inf,
    const float* __restrict__ e_data,
    const float* __restrict__ W1,   // (25,25) row-major fp32
    const float* __restrict__ B1,   // (25,)
    const float* __restrict__ W2,   // (20,25) row-major
    const float* __restrict__ B2,   // (20,)
    float*       __restrict__ out,  // fp32, 3 segments concatenated
    int E) {
  const int tid = threadIdx.x;
  const size_t base = (size_t)blockIdx.x * (BLK * M) + tid;

  // ---- gather 25 features for M edges (each round fully coalesced) ----
  float x[M][NUM_IN];
#pragma unroll
  for (int m = 0; m < M; ++m) {
    size_t e = base + (size_t)m * BLK;
    if (e < (size_t)E) {
      const float4* a4 = reinterpret_cast<const float4*>(a_data) + 2 * e;
      const float4* b4 = reinterpret_cast<const float4*>(b_data) + 2 * e;
      float4 a0 = a4[0], a1 = a4[1];
      float4 b0 = b4[0], b1v = b4[1];
      float4 ev = reinterpret_cast<const float4*>(e_data)[e];
      x[m][0]  = r[e];
      x[m][1]  = a0.x;  x[m][2]  = a0.y;  x[m][3]  = a0.z;  x[m][4]  = a0.w;
      x[m][5]  = a1.x;  x[m][6]  = a1.y;  x[m][7]  = a1.z;  x[m][8]  = a1.w;
      x[m][9]  = a_mat[e];
      x[m][10] = a_inf[e];
      x[m][11] = b0.x;  x[m][12] = b0.y;  x[m][13] = b0.z;  x[m][14] = b0.w;
      x[m][15] = b1v.x; x[m][16] = b1v.y; x[m][17] = b1v.z; x[m][18] = b1v.w;
      x[m][19] = b_mat[e];
      x[m][20] = b_inf[e];
      x[m][21] = ev.x;  x[m][22] = ev.y;  x[m][23] = ev.z;  x[m][24] = ev.w;
    } else {
#pragma unroll
      for (int k = 0; k < NUM_IN; ++k) x[m][k] = 0.0f;
    }
  }

  // ---- layer 1: h = relu(W1 @ x + b1); each weight feeds M FMA chains ----
  float h[M][NUM_IN];
#pragma unroll
  for (int j = 0; j < NUM_IN; ++j) {
    const float* wr = W1 + j * NUM_IN;
    float acc[M];
    float bj = B1[j];
#pragma unroll
    for (int m = 0; m < M; ++m) acc[m] = bj;
#pragma unroll
    for (int k = 0; k < NUM_IN; ++k) {
      float wk = wr[k];
#pragma unroll
      for (int m = 0; m < M; ++m) acc[m] = fmaf(wk, x[m][k], acc[m]);
    }
#pragma unroll
    for (int m = 0; m < M; ++m) h[m][j] = fmaxf(acc[m], 0.0f);
  }

  // ---- layer 2: y = relu(W2 @ h + b2) ----
  float y[M][NUM_OUT];
#pragma unroll
  for (int j = 0; j < NUM_OUT; ++j) {
    const float* wr = W2 + j * NUM_IN;
    float acc[M];
    float bj = B2[j];
#pragma unroll
    for (int m = 0; m < M; ++m) acc[m] = bj;
#pragma unroll
    for (int k = 0; k < NUM_IN; ++k) {
      float wk = wr[k];
#pragma unroll
      for (int m = 0; m < M; ++m) acc[m] = fmaf(wk, h[m][k], acc[m]);
    }
#pragma unroll
    for (int m = 0; m < M; ++m) y[m][j] = fmaxf(acc[m], 0.0f);
  }

  // ---- store fp32 into the 3 concatenated output segments ----
#pragma unroll
  for (int m = 0; m < M; ++m) {
    size_t e = base + (size_t)m * BLK;
    if (e < (size_t)E) {
      float4* o0 = reinterpret_cast<float4*>(out) + 2 * e;              // (E,8)
      o0[0] = make_float4(y[m][0], y[m][1], y[m][2],  y[m][3]);
      o0[1] = make_float4(y[m][4], y[m][5], y[m][6],  y[m][7]);
      float4* o1 = reinterpret_cast<float4*>(out + (size_t)8 * E) + 2 * e;
      o1[0] = make_float4(y[m][8],  y[m][9],  y[m][10], y[m][11]);
      o1[1] = make_float4(y[m][12], y[m][13], y[m][14], y[m][15]);
      reinterpret_cast<float4*>(out + (size_t)16 * E)[e] =              // (E,4)
          make_float4(y[m][16], y[m][17], y[m][18], y[m][19]);
    }
  }
}

extern "C" void kernel_launch(void* const* d_in, const int* in_sizes, int n_in,
                              void* d_out, int out_size, void* d_ws, size_t ws_size,
                              hipStream_t stream) {
  const float* r      = (const float*)d_in[0];
  const float* a_data = (const float*)d_in[1];
  const float* a_mat  = (const float*)d_in[2];
  const float* a_inf  = (const float*)d_in[3];
  const float* b_data = (const float*)d_in[4];
  const float* b_mat  = (const float*)d_in[5];
  const float* b_inf  = (const float*)d_in[6];
  const float* e_data = (const float*)d_in[7];
  const float* W1     = (const float*)d_in[8];
  const float* B1     = (const float*)d_in[9];
  const float* W2     = (const float*)d_in[10];
  const float* B2     = (const float*)d_in[11];
  int E = in_sizes[0];

  int edges_per_block = BLK * M;
  int grid = (E + edges_per_block - 1) / edges_per_block;
  edge_mlp<<<grid, BLK, 0, stream>>>(
      r, a_data, a_mat, a_inf, b_data, b_mat, b_inf, e_data,
      W1, B1, W2, B2, (float*)d_out, E);
}